// Round 10
// baseline (701.432 us; speedup 1.0000x reference)
//
#include <hip/hip_runtime.h>
#include <cmath>
#include <cstdint>

#define NB 32
#define NP 24564
#define NC 81
#define NEG_POS 3
#define BLOCKS_PER_ROW 96   // 96*256 = 24576 >= NP

static constexpr size_t MINED_ELEMS = (size_t)NB * NP;             // 786,048
static constexpr size_t MINED_BYTES = MINED_ELEMS * sizeof(float); // 3,144,192

// ws layout:
//   [0, MINED_BYTES)          float mined[NB*NP]
//   +0   double acc[3]        {loc_loss, ce_pos_sum, neg_sum}
//   +24  int num_pos[NB]
//   +24+4*NB       int tick[NB]
//   +24+8*NB       int gtick

__device__ __forceinline__ float wave_reduce_sum(float v) {
#pragma unroll
  for (int off = 32; off > 0; off >>= 1) v += __shfl_down(v, off, 64);
  return v;
}

__device__ __forceinline__ float smooth_l1_4(float4 a, float4 t) {
  float acc = 0.f, d, ax;
  d = a.x - t.x; ax = fabsf(d); acc += (ax < 1.f) ? 0.5f * d * d : ax - 0.5f;
  d = a.y - t.y; ax = fabsf(d); acc += (ax < 1.f) ? 0.5f * d * d : ax - 0.5f;
  d = a.z - t.z; ax = fabsf(d); acc += (ax < 1.f) ? 0.5f * d * d : ax - 0.5f;
  d = a.w - t.w; ax = fabsf(d); acc += (ax < 1.f) ? 0.5f * d * d : ax - 0.5f;
  return acc;
}

__global__ void mb_init(double* __restrict__ acc, int* __restrict__ ints) {
  // ints = num_pos[32] ++ tick[32] ++ gtick[1]
  int t = threadIdx.x;
  if (t < 3) acc[t] = 0.0;
  if (t < 2 * NB + 1) ints[t] = 0;
}

// Fused: CE pass (R1's proven scalar row-walk) + per-row last-finisher radix
// select + global last-finisher finalize. One big launch.
__global__ __launch_bounds__(256) void mb_fused(
    const float* __restrict__ loc_data, const float* __restrict__ conf_data,
    const float* __restrict__ loc_targets, const int* __restrict__ conf_targets,
    float* __restrict__ mined, double* __restrict__ acc,
    int* __restrict__ num_pos, int* __restrict__ tick, int* __restrict__ gtick,
    float* __restrict__ out) {
  const int b   = (int)blockIdx.y;
  const int tid = (int)threadIdx.x;
  const int p   = (int)blockIdx.x * 256 + tid;

  // ================= phase 1: CE + loc for my prior =================
  float loc_v = 0.f, ce_pos = 0.f, pcnt = 0.f;

  if (p < NP) {
    const size_t idx = (size_t)b * NP + p;
    const int tgt = conf_targets[idx];
    const float* __restrict__ rowp = conf_data + idx * (size_t)NC;
    const float tv = rowp[tgt];

    float s = 0.f;
#pragma unroll 27
    for (int c = 0; c < NC; ++c) s += __expf(rowp[c]);

    const float ce = __logf(s) - tv;   // unstabilized LSE safe: logits ~N(0,1)
    const int is_pos = tgt > 0;
    mined[idx] = is_pos ? 0.f : ce;    // ce > 0 always; bits order as floats
    if (is_pos) {
      pcnt = 1.f;
      ce_pos = ce;
      loc_v = smooth_l1_4(*reinterpret_cast<const float4*>(loc_data + idx * 4),
                          *reinterpret_cast<const float4*>(loc_targets + idx * 4));
    }
  }

  {  // block reduction
    __shared__ float red[3][4];
    const int lane = tid & 63, wid = tid >> 6;
    float r0 = wave_reduce_sum(loc_v);
    float r1 = wave_reduce_sum(ce_pos);
    float r2 = wave_reduce_sum(pcnt);
    if (lane == 0) { red[0][wid] = r0; red[1][wid] = r1; red[2][wid] = r2; }
    __syncthreads();
    if (tid == 0) {
      float t0 = 0.f, t1 = 0.f, t2 = 0.f;
#pragma unroll
      for (int i = 0; i < 4; ++i) { t0 += red[0][i]; t1 += red[1][i]; t2 += red[2][i]; }
      if (t0 != 0.f) atomicAdd(&acc[0], (double)t0);
      if (t1 != 0.f) atomicAdd(&acc[1], (double)t1);
      const int np_ = (int)t2;
      if (np_) atomicAdd(&num_pos[b], np_);
    }
  }

  // ================= ticket: last block of row b proceeds =================
  __shared__ int am_last;
  __threadfence();   // publish mined stores + atomics (device scope)
  if (tid == 0) am_last = (atomicAdd(&tick[b], 1) == BLOCKS_PER_ROW - 1) ? 1 : 0;
  __syncthreads();
  if (!am_last) return;
  __threadfence();   // acquire: row b's mined/num_pos now visible to this block

  // ================= phase 2: radix select for row b (256 threads) =========
  const float* __restrict__ row = mined + (size_t)b * NP;
  const int wid = tid >> 6;   // 4 waves

  __shared__ int hist[4][256];
  __shared__ int total[256];
  __shared__ int suffix[256];
  __shared__ unsigned s_prefix;
  __shared__ int s_k;

  if (tid == 0) {
    int k = NEG_POS * num_pos[b];
    if (k > NP - 1) k = NP - 1;
    s_k = k;          // 0-indexed rank, descending order
    s_prefix = 0u;
  }
  __syncthreads();

  for (int shift = 24; shift >= 0; shift -= 8) {
#pragma unroll
    for (int i = 0; i < 4; ++i) hist[i][tid] = 0;
    __syncthreads();
    const unsigned mask = (shift == 24) ? 0u : (0xFFFFFFFFu << (shift + 8));
    const unsigned pfx = s_prefix;
    const int kcur = s_k;

    for (int q = tid; q < NP / 4; q += 256) {
      const float4 v = reinterpret_cast<const float4*>(row)[q];
      unsigned u;
      u = __float_as_uint(v.x); if ((u & mask) == pfx) atomicAdd(&hist[wid][(u >> shift) & 255], 1);
      u = __float_as_uint(v.y); if ((u & mask) == pfx) atomicAdd(&hist[wid][(u >> shift) & 255], 1);
      u = __float_as_uint(v.z); if ((u & mask) == pfx) atomicAdd(&hist[wid][(u >> shift) & 255], 1);
      u = __float_as_uint(v.w); if ((u & mask) == pfx) atomicAdd(&hist[wid][(u >> shift) & 255], 1);
    }
    __syncthreads();

    {
      int t = hist[0][tid] + hist[1][tid] + hist[2][tid] + hist[3][tid];
      total[tid] = t;
      suffix[tid] = t;
    }
    __syncthreads();
    for (int d = 1; d < 256; d <<= 1) {
      int v = suffix[tid];
      if (tid + d < 256) v += suffix[tid + d];
      __syncthreads();
      suffix[tid] = v;
      __syncthreads();
    }
    {
      const int cs = suffix[tid] - total[tid];   // count strictly above this bin
      if (kcur >= cs && kcur < cs + total[tid]) {
        s_prefix = pfx | ((unsigned)tid << shift);
        s_k = kcur - cs;
      }
    }
    __syncthreads();
  }

  const unsigned vbits = s_prefix;  // exact pivot bit pattern
  float nsum = 0.f;
  for (int q = tid; q < NP / 4; q += 256) {
    const float4 v = reinterpret_cast<const float4*>(row)[q];
    if (__float_as_uint(v.x) > vbits) nsum += v.x;
    if (__float_as_uint(v.y) > vbits) nsum += v.y;
    if (__float_as_uint(v.z) > vbits) nsum += v.z;
    if (__float_as_uint(v.w) > vbits) nsum += v.w;
  }

  __shared__ float wsum[4];
  float w = wave_reduce_sum(nsum);
  if ((tid & 63) == 0) wsum[tid >> 6] = w;
  __syncthreads();

  // ================= phase 3: global last-finisher writes out =============
  if (tid == 0) {
    atomicAdd(&acc[2], (double)(wsum[0] + wsum[1] + wsum[2] + wsum[3]));
    __threadfence();
    if (atomicAdd(gtick, 1) == NB - 1) {
      __threadfence();
      int tot = 0;
#pragma unroll
      for (int i = 0; i < NB; ++i) tot += num_pos[i];
      const double n = (double)(tot > 0 ? tot : 1);
      out[0] = (float)((acc[0] + acc[1] + acc[2]) / n);
    }
  }
}

extern "C" void kernel_launch(void* const* d_in, const int* in_sizes, int n_in,
                              void* d_out, int out_size, void* d_ws, size_t ws_size,
                              hipStream_t stream) {
  const float* loc_data     = (const float*)d_in[0];
  const float* conf_data    = (const float*)d_in[1];
  const float* loc_targets  = (const float*)d_in[2];
  const int*   conf_targets = (const int*)d_in[3];
  float* out = (float*)d_out;

  float*  mined = (float*)d_ws;
  double* acc   = (double*)((char*)d_ws + MINED_BYTES);
  int*    ints  = (int*)((char*)d_ws + MINED_BYTES + 3 * sizeof(double));
  int*    num_pos = ints;
  int*    tick    = ints + NB;
  int*    gtick   = ints + 2 * NB;

  mb_init<<<1, 96, 0, stream>>>(acc, ints);

  dim3 grid(BLOCKS_PER_ROW, NB);
  mb_fused<<<grid, 256, 0, stream>>>(loc_data, conf_data, loc_targets,
                                     conf_targets, mined, acc, num_pos,
                                     tick, gtick, out);
}

// Round 11
// 197.039 us; speedup vs baseline: 3.5599x; 3.5599x over previous
//
#include <hip/hip_runtime.h>
#include <cmath>
#include <cstdint>

#define NB 32
#define NP 24564
#define NC 81
#define NEG_POS 3

static constexpr size_t MINED_ELEMS = (size_t)NB * NP;             // 786,048
static constexpr size_t MINED_BYTES = MINED_ELEMS * sizeof(float); // 3,144,192
static constexpr uint32_t CONF_BYTES = (uint32_t)(MINED_ELEMS * NC * 4); // 254,679,552

#define TILE_ROWS 64
#define TILE_BYTES (TILE_ROWS * NC * 4)          // 20,736
#define NTILES ((int)(MINED_ELEMS / TILE_ROWS))  // 12,282 exact
#define TILES_PER_BLOCK 6
#define MAIN_BLOCKS (NTILES / TILES_PER_BLOCK)   // 2,047 exact
#define LDS_FLOATS 6144                          // 24,576 B staged region (>= TILE_BYTES)

// ws layout:
//   [0, MINED_BYTES)                    float mined[NB*NP]
//   [MINED_BYTES, +24)                  double acc[3]  {loc_loss, ce_pos_sum, neg_sum}
//   [MINED_BYTES+24, +24+4*NB)          int   num_pos[NB]

__device__ __forceinline__ float wave_reduce_sum(float v) {
#pragma unroll
  for (int off = 32; off > 0; off >>= 1) v += __shfl_down(v, off, 64);
  return v;
}

__device__ __forceinline__ float smooth_l1_4(float4 a, float4 t) {
  float acc = 0.f, d, ax;
  d = a.x - t.x; ax = fabsf(d); acc += (ax < 1.f) ? 0.5f * d * d : ax - 0.5f;
  d = a.y - t.y; ax = fabsf(d); acc += (ax < 1.f) ? 0.5f * d * d : ax - 0.5f;
  d = a.z - t.z; ax = fabsf(d); acc += (ax < 1.f) ? 0.5f * d * d : ax - 0.5f;
  d = a.w - t.w; ax = fabsf(d); acc += (ax < 1.f) ? 0.5f * d * d : ax - 0.5f;
  return acc;
}

__global__ void mb_init(double* __restrict__ acc, int* __restrict__ num_pos) {
  int t = threadIdx.x;
  if (t < 3) acc[t] = 0.0;
  if (t < NB) num_pos[t] = 0;
}

// Async stage one 64-row tile (20,736 B; issues 24,576 B, tail clamped) into
// LDS via global_load_lds width=16. Fire-and-forget: no VGPR round trip, the
// only wait is the explicit vmcnt(0) at phase end.
__device__ __forceinline__ void stage_tile(const char* __restrict__ conf_base,
                                           uint32_t tile, float* buf,
                                           int wid, int lane) {
  const uint32_t SAFE = CONF_BYTES - 16;
  uint32_t off0 = tile * (uint32_t)TILE_BYTES + (uint32_t)(wid * 6144 + lane * 16);
#pragma unroll
  for (int i = 0; i < 6; ++i) {
    uint32_t off = off0 + (uint32_t)(i * 1024);
    off = (off <= SAFE) ? off : SAFE;            // per-lane clamp (last tile only)
    const void* g = conf_base + off;
    float* l = buf + wid * 1536 + i * 256;       // wave-uniform LDS base
    __builtin_amdgcn_global_load_lds(
        (const __attribute__((address_space(1))) void*)g,
        (__attribute__((address_space(3))) void*)l, 16, 0, 0);
  }
}

// Compute one tile from LDS: row = tid>>2 owns a row with 4 lanes; part p
// sums classes [20p, 20p+20) (+ class 80 on part 3); quad shfl_xor reduce.
__device__ __forceinline__ void compute_tile(
    const float* __restrict__ L, int tile, int tgt, int row, int part,
    const float* __restrict__ loc_data, const float* __restrict__ loc_targets,
    float* __restrict__ mined, int* __restrict__ num_pos,
    float& loc_v, float& ce_pos) {
  const float* rp = L + row * NC + part * 20;
  float s = 0.f;
#pragma unroll
  for (int j = 0; j < 20; ++j) s += __expf(rp[j]);
  if (part == 3) s += __expf(L[row * NC + 80]);
  s += __shfl_xor(s, 1, 64);
  s += __shfl_xor(s, 2, 64);
  if (part == 0) {
    const float tv = L[row * NC + tgt];
    const float ce = __logf(s) - tv;             // unstabilized LSE safe: |x| < ~6
    const size_t flat = (size_t)tile * TILE_ROWS + row;
    const int is_pos = tgt > 0;
    mined[flat] = is_pos ? 0.f : ce;             // ce > 0; bits order as floats
    if (is_pos) {
      ce_pos += ce;
      loc_v += smooth_l1_4(*reinterpret_cast<const float4*>(loc_data + flat * 4),
                           *reinterpret_cast<const float4*>(loc_targets + flat * 4));
      atomicAdd(&num_pos[(int)(flat / NP)], 1);
    }
  }
}

#define DRAIN_BARRIER()                                \
  do {                                                 \
    asm volatile("s_waitcnt vmcnt(0)" ::: "memory");   \
    __builtin_amdgcn_s_barrier();                      \
  } while (0)

__global__ __launch_bounds__(256) void mb_main(
    const float* __restrict__ loc_data, const float* __restrict__ conf_data,
    const float* __restrict__ loc_targets, const int* __restrict__ conf_targets,
    float* __restrict__ mined, double* __restrict__ acc, int* __restrict__ num_pos) {
  __shared__ float ldsA[LDS_FLOATS];   // two separate symbols: compile-time
  __shared__ float ldsB[LDS_FLOATS];   // buffer selection, clean aliasing

  const int tid = (int)threadIdx.x;
  const int wid = tid >> 6, lane = tid & 63;
  const int row = tid >> 2, part = tid & 3;
  const int t0 = (int)blockIdx.x * TILES_PER_BLOCK;
  const char* cbase = (const char*)conf_data;

  float loc_v = 0.f, ce_pos = 0.f;

  // prologue: stage tile t0 into A
  stage_tile(cbase, (uint32_t)t0, ldsA, wid, lane);
  int tgtA = conf_targets[(size_t)t0 * TILE_ROWS + row];
  int tgtB = 0;
  DRAIN_BARRIER();

#pragma unroll
  for (int u = 0; u < 3; ++u) {
    const int tA = t0 + 2 * u;

    // phase 1: stage B(tA+1) || compute A(tA)
    stage_tile(cbase, (uint32_t)(tA + 1), ldsB, wid, lane);
    tgtB = conf_targets[(size_t)(tA + 1) * TILE_ROWS + row];
    compute_tile(ldsA, tA, tgtA, row, part, loc_data, loc_targets,
                 mined, num_pos, loc_v, ce_pos);
    DRAIN_BARRIER();

    // phase 2: stage A(tA+2) || compute B(tA+1)
    if (u < 2) {
      stage_tile(cbase, (uint32_t)(tA + 2), ldsA, wid, lane);
      tgtA = conf_targets[(size_t)(tA + 2) * TILE_ROWS + row];
    }
    compute_tile(ldsB, tA + 1, tgtB, row, part, loc_data, loc_targets,
                 mined, num_pos, loc_v, ce_pos);
    if (u < 2) DRAIN_BARRIER();
  }

  // block reduction for the two global sums
  __shared__ float red[2][4];
  float r0 = wave_reduce_sum(loc_v);
  float r1 = wave_reduce_sum(ce_pos);
  if (lane == 0) { red[0][wid] = r0; red[1][wid] = r1; }
  __syncthreads();
  if (tid == 0) {
    float s0 = 0.f, s1 = 0.f;
#pragma unroll
    for (int i = 0; i < 4; ++i) { s0 += red[0][i]; s1 += red[1][i]; }
    if (s0 != 0.f) atomicAdd(&acc[0], (double)s0);
    if (s1 != 0.f) atomicAdd(&acc[1], (double)s1);
  }
}

// One block per batch row: radix-select the (k+1)-th largest of mined[b,:]
// (k = min(3*num_pos, NP-1)), then sum elements strictly greater.
// Suffix scan done by wave 0 alone (quad-local + shfl_down lane scan):
// 2 barriers per radix pass instead of 16.
__global__ __launch_bounds__(1024) void mb_select(
    const float* __restrict__ mined, const int* __restrict__ num_pos,
    double* __restrict__ acc) {
  const int b = blockIdx.x;
  const float* __restrict__ row = mined + (size_t)b * NP;
  const int tid = threadIdx.x;
  const int wid = tid >> 6;  // 16 waves
  const int lane = tid & 63;

  __shared__ int hist[16][256];   // per-wave histograms (16 KB)
  __shared__ int total[256];
  __shared__ int suffix[256];
  __shared__ unsigned s_prefix;
  __shared__ int s_k;

  if (tid == 0) {
    int k = NEG_POS * num_pos[b];
    if (k > NP - 1) k = NP - 1;
    s_k = k;          // 0-indexed rank, descending order
    s_prefix = 0u;
  }
  __syncthreads();

  for (int shift = 24; shift >= 0; shift -= 8) {
    for (int i = tid; i < 16 * 256; i += 1024) ((int*)hist)[i] = 0;
    __syncthreads();
    const unsigned mask = (shift == 24) ? 0u : (0xFFFFFFFFu << (shift + 8));
    const unsigned pfx = s_prefix;
    const int kcur = s_k;

    for (int q = tid; q < NP / 4; q += 1024) {
      const float4 v = reinterpret_cast<const float4*>(row)[q];
      unsigned u;
      u = __float_as_uint(v.x); if ((u & mask) == pfx) atomicAdd(&hist[wid][(u >> shift) & 255], 1);
      u = __float_as_uint(v.y); if ((u & mask) == pfx) atomicAdd(&hist[wid][(u >> shift) & 255], 1);
      u = __float_as_uint(v.z); if ((u & mask) == pfx) atomicAdd(&hist[wid][(u >> shift) & 255], 1);
      u = __float_as_uint(v.w); if ((u & mask) == pfx) atomicAdd(&hist[wid][(u >> shift) & 255], 1);
    }
    __syncthreads();

    if (tid < 256) {
      int t = 0;
#pragma unroll
      for (int w = 0; w < 16; ++w) t += hist[w][tid];
      total[tid] = t;
    }
    __syncthreads();

    // wave 0: inclusive suffix sum of total[256]; lane owns bins 4l..4l+3
    if (wid == 0) {
      const int t0_ = total[4 * lane + 0];
      const int t1_ = total[4 * lane + 1];
      const int t2_ = total[4 * lane + 2];
      const int t3_ = total[4 * lane + 3];
      const int s3 = t3_;
      const int s2 = t2_ + s3;
      const int s1 = t1_ + s2;
      const int s0 = t0_ + s1;
      int acc_ = s0;  // quad sum
#pragma unroll
      for (int off = 1; off < 64; off <<= 1) {
        const int o = __shfl_down(acc_, off, 64);
        if (lane + off < 64) acc_ += o;
      }
      const int excl = acc_ - s0;   // sum of all higher lanes' quads
      suffix[4 * lane + 0] = s0 + excl;
      suffix[4 * lane + 1] = s1 + excl;
      suffix[4 * lane + 2] = s2 + excl;
      suffix[4 * lane + 3] = s3 + excl;
    }
    __syncthreads();

    if (tid < 256) {
      const int cs = suffix[tid] - total[tid];   // count strictly above this bin
      if (kcur >= cs && kcur < cs + total[tid]) {
        s_prefix = pfx | ((unsigned)tid << shift);
        s_k = kcur - cs;
      }
    }
    __syncthreads();
  }

  const unsigned vbits = s_prefix;  // exact pivot bit pattern
  float sum = 0.f;
  for (int q = tid; q < NP / 4; q += 1024) {
    const float4 v = reinterpret_cast<const float4*>(row)[q];
    if (__float_as_uint(v.x) > vbits) sum += v.x;
    if (__float_as_uint(v.y) > vbits) sum += v.y;
    if (__float_as_uint(v.z) > vbits) sum += v.z;
    if (__float_as_uint(v.w) > vbits) sum += v.w;
  }

  __shared__ float wsum[16];
  float w = wave_reduce_sum(sum);
  if (lane == 0) wsum[wid] = w;
  __syncthreads();
  if (tid == 0) {
    float t = 0.f;
#pragma unroll
    for (int i = 0; i < 16; ++i) t += wsum[i];
    atomicAdd(&acc[2], (double)t);
  }
}

__global__ void mb_finalize(const double* __restrict__ acc,
                            const int* __restrict__ num_pos,
                            float* __restrict__ out) {
  if (threadIdx.x == 0) {
    int tot = 0;
#pragma unroll
    for (int i = 0; i < NB; ++i) tot += num_pos[i];
    const double n = (double)(tot > 0 ? tot : 1);
    out[0] = (float)((acc[0] + acc[1] + acc[2]) / n);
  }
}

extern "C" void kernel_launch(void* const* d_in, const int* in_sizes, int n_in,
                              void* d_out, int out_size, void* d_ws, size_t ws_size,
                              hipStream_t stream) {
  const float* loc_data     = (const float*)d_in[0];
  const float* conf_data    = (const float*)d_in[1];
  const float* loc_targets  = (const float*)d_in[2];
  const int*   conf_targets = (const int*)d_in[3];
  float* out = (float*)d_out;

  float*  mined   = (float*)d_ws;
  double* acc     = (double*)((char*)d_ws + MINED_BYTES);
  int*    num_pos = (int*)((char*)d_ws + MINED_BYTES + 3 * sizeof(double));

  mb_init<<<1, 64, 0, stream>>>(acc, num_pos);

  mb_main<<<MAIN_BLOCKS, 256, 0, stream>>>(loc_data, conf_data, loc_targets,
                                           conf_targets, mined, acc, num_pos);

  mb_select<<<NB, 1024, 0, stream>>>(mined, num_pos, acc);

  mb_finalize<<<1, 64, 0, stream>>>(acc, num_pos, out);
}